// Round 18
// baseline (118.239 us; speedup 1.0000x reference)
//
#include <hip/hip_runtime.h>
#include <math.h>

#define DM 192
#define RNK 12
#define NS 16
#define NO2 432

// workspace float offsets (41.5 MB footprint)
#define OFF_FLAG   156672u
#define OFF_XH     156688u            // x bf16-hi planes, 1572864 shorts (in ex-PY spare)
#define OFF_XL     943120u            // x bf16-lo planes, 1572864 shorts
#define OFF_YG     3302416u           // scan output (fused ysum), row-major planes [bd][4096] f32
#define OFF_DIAG   5268496u           // 384 u diag planes [bd][4096] f32 (proj writes directly)
#define OFF_TL2    6841360u           // 384 (dT,dL) float2 diag planes [bd][8192] f32
#define OFF_BC4D   9987088u           // 24 f32 float4-cell diag planes [b*12+grp][4096][4]

typedef __attribute__((ext_vector_type(8))) short short8v;
typedef __attribute__((ext_vector_type(4))) float floatx4;

__device__ __forceinline__ float gelu_f(float x){
    return 0.5f * x * (1.0f + erff(x * 0.70710678118654752f));
}
__device__ __forceinline__ float softplus_f(float x){
    return fmaxf(x, 0.0f) + log1pf(__expf(-fabsf(x)));
}
__device__ __forceinline__ int diag_off(int s){
    return (s <= 64) ? ((s * (s + 1)) >> 1) : (2080 + (((s - 64) * (191 - s)) >> 1));
}
// inverse map: packed index q -> (i,j)
__device__ __forceinline__ void inv_diag(int q, int& i_out, int& j_out){
    int s;
    if (q < 2080){
        s = (int)((sqrtf(8.0f * (float)q + 1.0f) - 1.0f) * 0.5f);
        while (((s + 1) * (s + 2)) / 2 <= q) s++;
        while ((s * (s + 1)) / 2 > q) s--;
    } else {
        const int q2 = 4095 - q;
        int t = (int)((sqrtf(8.0f * (float)q2 + 1.0f) - 1.0f) * 0.5f);
        while (((t + 1) * (t + 2)) / 2 <= q2) t++;
        while ((t * (t + 1)) / 2 > q2) t--;
        s = 126 - t;
    }
    const int jmin = (s > 63) ? (s - 63) : 0;
    const int j = jmin + (q - diag_off(s));
    j_out = j;
    i_out = s - j;
}
__device__ __forceinline__ unsigned short bf16_rte(float f){
    unsigned u = __float_as_uint(f);
    unsigned r = (u + 0x7fffu + ((u >> 16) & 1u)) >> 16;
    return (unsigned short)r;
}
__device__ __forceinline__ float bf16_f(unsigned short h){
    return __uint_as_float(((unsigned)h) << 16);
}
__device__ __forceinline__ void split8(float4 v0, float4 v1, short8v& hi, short8v& lo){
    float f[8] = {v0.x, v0.y, v0.z, v0.w, v1.x, v1.y, v1.z, v1.w};
    #pragma unroll
    for (int e = 0; e < 8; e++){
        unsigned short h = bf16_rte(f[e]);
        hi[e] = (short)h;
        lo[e] = (short)bf16_rte(f[e] - bf16_f(h));
    }
}

// ---------------- prep: bf16 hi/lo weight splits + A-structure flag ----------------
#define SW_WINH 0u
#define SW_WINL 36864u
#define SW_WCH  73728u
#define SW_WCL  156672u
#define SW_WOH  239616u
#define SW_WOL  276480u

__global__ __launch_bounds__(256) void prep_k(const float* __restrict__ Win,
                                              const float* __restrict__ xpw,
                                              const float* __restrict__ dtwT,
                                              const float* __restrict__ dtwL,
                                              const float* __restrict__ Wout,
                                              const float* __restrict__ ATl,
                                              const float* __restrict__ ALl,
                                              float* __restrict__ ws){
    unsigned short* __restrict__ wsu = (unsigned short*)ws;
    if (blockIdx.x == 612){
        __shared__ int okf;
        if (threadIdx.x == 0) okf = 1;
        __syncthreads();
        bool ok = true;
        for (int t = threadIdx.x; t < 6144; t += 256){
            const float* arr = (t < 3072) ? ATl : ALl;
            int e = (t < 3072) ? t : t - 3072;
            int n = e & 15;
            ok = ok && (fabsf(arr[e] - logf((float)(n + 1))) < 1e-5f);
        }
        if (!ok) atomicAnd(&okf, 0);
        __syncthreads();
        if (threadIdx.x == 0) ws[OFF_FLAG] = okf ? 1.0f : 0.0f;
        return;
    }
    int idx = blockIdx.x * 256 + threadIdx.x;
    float w;
    unsigned hioff, looff, rel;
    if (idx < 36864){
        w = Win[idx]; hioff = SW_WINH; looff = SW_WINL; rel = idx;
    } else if (idx < 119808){
        int t = idx - 36864;
        int o = t / DM, c = t - o * DM;
        float acc = 0.f;
        if (o < 192){
            #pragma unroll
            for (int r = 0; r < RNK; r++) acc += dtwT[o * RNK + r] * xpw[r * DM + c];
        } else if (o < 384){
            int d2 = o - 192;
            #pragma unroll
            for (int r = 0; r < RNK; r++) acc += dtwL[d2 * RNK + r] * xpw[(RNK + r) * DM + c];
        } else {
            acc = xpw[(2 * RNK + (o - 384)) * DM + c];
        }
        w = acc; hioff = SW_WCH; looff = SW_WCL; rel = t;
    } else if (idx < 156672){
        int t = idx - 119808;
        w = Wout[t]; hioff = SW_WOH; looff = SW_WOL; rel = t;
    } else return;
    unsigned short h = bf16_rte(w);
    wsu[hioff + rel] = h;
    wsu[looff + rel] = bf16_rte(w - bf16_f(h));
}

// ---------------- x pre-split: f32 -> bf16 hi/lo short planes (streaming) ----------------
__global__ __launch_bounds__(256) void xsplit_k(const float* __restrict__ x,
                                                float* __restrict__ ws){
    unsigned short* __restrict__ xh = (unsigned short*)(ws + OFF_XH);
    unsigned short* __restrict__ xl = (unsigned short*)(ws + OFF_XL);
    const int i0 = (blockIdx.x * 256 + threadIdx.x) * 4;   // 1536 blocks x 256 thr x 4
    const float4 v = *(const float4*)&x[i0];
    ushort4 hv, lv;
    const float f[4] = {v.x, v.y, v.z, v.w};
    unsigned short hh[4], ll[4];
    #pragma unroll
    for (int e = 0; e < 4; e++){
        hh[e] = bf16_rte(f[e]);
        ll[e] = bf16_rte(f[e] - bf16_f(hh[e]));
    }
    hv = make_ushort4(hh[0], hh[1], hh[2], hh[3]);
    lv = make_ushort4(ll[0], ll[1], ll[2], ll[3]);
    *(ushort4*)&xh[i0] = hv;
    *(ushort4*)&xl[i0] = lv;
}

// ---------------- fused projections via bf16x3 MFMA, 32 pos/block, DIAG-DIRECT stores ----
// x fragments loaded pre-split (no split8 for G1).
__global__ __launch_bounds__(256, 1) void proj_k(const float* __restrict__ inb,
                                                 const float* __restrict__ dtTb,
                                                 const float* __restrict__ dtLb,
                                                 float* __restrict__ ws){
    __shared__ float u_t[32][196];              // 25 KB
    __shared__ float g2[32][436];               // 56 KB
    const unsigned short* __restrict__ wsu = (const unsigned short*)ws;
    const unsigned short* __restrict__ xhp = (const unsigned short*)(ws + OFF_XH);
    const unsigned short* __restrict__ xlp = (const unsigned short*)(ws + OFF_XL);
    const int bx = blockIdx.x;
    const int b = bx >> 7;
    const int Q0 = (bx & 127) * 32;
    const int tid = threadIdx.x;
    const int wv = tid >> 6, lane = tid & 63;
    const int lr = lane & 15, lg = lane >> 4;

    int ic0, jc0, ic1, jc1;
    inv_diag(Q0 + lr, ic0, jc0);
    inv_diag(Q0 + 16 + lr, ic1, jc1);
    const size_t xrow0 = ((size_t)(b << 12) + (size_t)(ic0 * 64 + jc0)) * 192;
    const size_t xrow1 = ((size_t)(b << 12) + (size_t)(ic1 * 64 + jc1)) * 192;

    // ---- G1: u = gelu(x @ Win^T + b), two pos-groups, pre-split x fragments ----
    short8v xh0[6], xl0[6], xh1[6], xl1[6];
    #pragma unroll
    for (int ks = 0; ks < 6; ks++){
        const size_t o0 = xrow0 + ks * 32 + lg * 8;
        const size_t o1 = xrow1 + ks * 32 + lg * 8;
        xh0[ks] = *(const short8v*)(xhp + o0);
        xl0[ks] = *(const short8v*)(xlp + o0);
        xh1[ks] = *(const short8v*)(xhp + o1);
        xl1[ks] = *(const short8v*)(xlp + o1);
    }
    {
        floatx4 a00 = {0,0,0,0}, a01 = {0,0,0,0}, a02 = {0,0,0,0};
        floatx4 a10 = {0,0,0,0}, a11 = {0,0,0,0}, a12 = {0,0,0,0};
        const int n0 = wv * 48;
        #pragma unroll
        for (int ks = 0; ks < 6; ks++){
            const size_t rb = (size_t)(n0 + lr) * 192 + ks * 32 + lg * 8;
            const short8v bh0 = *(const short8v*)(wsu + SW_WINH + rb);
            const short8v bl0 = *(const short8v*)(wsu + SW_WINL + rb);
            const short8v bh1 = *(const short8v*)(wsu + SW_WINH + rb + 16*192);
            const short8v bl1 = *(const short8v*)(wsu + SW_WINL + rb + 16*192);
            const short8v bh2 = *(const short8v*)(wsu + SW_WINH + rb + 32*192);
            const short8v bl2 = *(const short8v*)(wsu + SW_WINL + rb + 32*192);
            a00 = __builtin_amdgcn_mfma_f32_16x16x32_bf16(xh0[ks], bh0, a00, 0, 0, 0);
            a10 = __builtin_amdgcn_mfma_f32_16x16x32_bf16(xh1[ks], bh0, a10, 0, 0, 0);
            a01 = __builtin_amdgcn_mfma_f32_16x16x32_bf16(xh0[ks], bh1, a01, 0, 0, 0);
            a11 = __builtin_amdgcn_mfma_f32_16x16x32_bf16(xh1[ks], bh1, a11, 0, 0, 0);
            a02 = __builtin_amdgcn_mfma_f32_16x16x32_bf16(xh0[ks], bh2, a02, 0, 0, 0);
            a12 = __builtin_amdgcn_mfma_f32_16x16x32_bf16(xh1[ks], bh2, a12, 0, 0, 0);
            a00 = __builtin_amdgcn_mfma_f32_16x16x32_bf16(xh0[ks], bl0, a00, 0, 0, 0);
            a10 = __builtin_amdgcn_mfma_f32_16x16x32_bf16(xh1[ks], bl0, a10, 0, 0, 0);
            a01 = __builtin_amdgcn_mfma_f32_16x16x32_bf16(xh0[ks], bl1, a01, 0, 0, 0);
            a11 = __builtin_amdgcn_mfma_f32_16x16x32_bf16(xh1[ks], bl1, a11, 0, 0, 0);
            a02 = __builtin_amdgcn_mfma_f32_16x16x32_bf16(xh0[ks], bl2, a02, 0, 0, 0);
            a12 = __builtin_amdgcn_mfma_f32_16x16x32_bf16(xh1[ks], bl2, a12, 0, 0, 0);
            a00 = __builtin_amdgcn_mfma_f32_16x16x32_bf16(xl0[ks], bh0, a00, 0, 0, 0);
            a10 = __builtin_amdgcn_mfma_f32_16x16x32_bf16(xl1[ks], bh0, a10, 0, 0, 0);
            a01 = __builtin_amdgcn_mfma_f32_16x16x32_bf16(xl0[ks], bh1, a01, 0, 0, 0);
            a11 = __builtin_amdgcn_mfma_f32_16x16x32_bf16(xl1[ks], bh1, a11, 0, 0, 0);
            a02 = __builtin_amdgcn_mfma_f32_16x16x32_bf16(xl0[ks], bh2, a02, 0, 0, 0);
            a12 = __builtin_amdgcn_mfma_f32_16x16x32_bf16(xl1[ks], bh2, a12, 0, 0, 0);
        }
        const float b0 = inb[n0 + lr], b1 = inb[n0 + 16 + lr], b2 = inb[n0 + 32 + lr];
        #pragma unroll
        for (int r = 0; r < 4; r++){
            const int pl = lg * 4 + r;
            u_t[pl][n0 + lr]           = gelu_f(a00[r] + b0);
            u_t[pl][n0 + 16 + lr]      = gelu_f(a01[r] + b1);
            u_t[pl][n0 + 32 + lr]      = gelu_f(a02[r] + b2);
            u_t[16 + pl][n0 + lr]      = gelu_f(a10[r] + b0);
            u_t[16 + pl][n0 + 16 + lr] = gelu_f(a11[r] + b1);
            u_t[16 + pl][n0 + 32 + lr] = gelu_f(a12[r] + b2);
        }
    }
    __syncthreads();

    // coalesced u diag-plane stores (f32): 3 plane passes x 2 pos halves
    {
        float* __restrict__ u_dg = ws + OFF_DIAG;
        #pragma unroll
        for (int pass = 0; pass < 3; pass++){
            const int plane = pass * 64 + (tid >> 2);
            const int posq = (tid & 3) * 4;
            #pragma unroll
            for (int hf = 0; hf < 2; hf++){
                const int pq = hf * 16 + posq;
                float4 v = make_float4(u_t[pq + 0][plane], u_t[pq + 1][plane],
                                       u_t[pq + 2][plane], u_t[pq + 3][plane]);
                *(float4*)&u_dg[(size_t)(b * 192 + plane) * 4096 + Q0 + pq] = v;
            }
        }
    }

    // ---- G2: [dT | dL | BC] = u @ Wcomb^T, two pos-groups ----
    short8v uh0[6], ul0[6], uh1[6], ul1[6];
    #pragma unroll
    for (int ks = 0; ks < 6; ks++){
        const float* up0 = &u_t[lr][ks * 32 + lg * 8];
        const float* up1 = &u_t[16 + lr][ks * 32 + lg * 8];
        split8(*(const float4*)up0, *(const float4*)(up0 + 4), uh0[ks], ul0[ks]);
        split8(*(const float4*)up1, *(const float4*)(up1 + 4), uh1[ks], ul1[ks]);
    }
    const int t0 = wv * 7;
    const int cnt = (wv == 3) ? 6 : 7;
    for (int tp = 0; tp < cnt; tp++){
        const int n0a = (t0 + tp) * 16;
        floatx4 g0 = {0,0,0,0}, g1 = {0,0,0,0};
        #pragma unroll
        for (int ks = 0; ks < 6; ks++){
            const size_t ra = (size_t)(n0a + lr) * 192 + ks * 32 + lg * 8;
            const short8v bhA = *(const short8v*)(wsu + SW_WCH + ra);
            const short8v blA = *(const short8v*)(wsu + SW_WCL + ra);
            g0 = __builtin_amdgcn_mfma_f32_16x16x32_bf16(uh0[ks], bhA, g0, 0, 0, 0);
            g1 = __builtin_amdgcn_mfma_f32_16x16x32_bf16(uh1[ks], bhA, g1, 0, 0, 0);
            g0 = __builtin_amdgcn_mfma_f32_16x16x32_bf16(uh0[ks], blA, g0, 0, 0, 0);
            g1 = __builtin_amdgcn_mfma_f32_16x16x32_bf16(uh1[ks], blA, g1, 0, 0, 0);
            g0 = __builtin_amdgcn_mfma_f32_16x16x32_bf16(ul0[ks], bhA, g0, 0, 0, 0);
            g1 = __builtin_amdgcn_mfma_f32_16x16x32_bf16(ul1[ks], bhA, g1, 0, 0, 0);
        }
        const int o = n0a + lr;
        float bb = 0.f; int mode = 2;
        if (o < 192){ bb = dtTb[o]; mode = 0; }
        else if (o < 384){ bb = dtLb[o - 192]; mode = 1; }
        #pragma unroll
        for (int r = 0; r < 4; r++){
            float v0 = g0[r], v1 = g1[r];
            if (mode < 2){ v0 = softplus_f(v0 + bb); v1 = softplus_f(v1 + bb); }
            g2[lg * 4 + r][o] = v0;
            g2[16 + lg * 4 + r][o] = v1;
        }
    }
    __syncthreads();

    // coalesced interleaved (dT,dL) diag stores + BC diag stores
    {
        float* __restrict__ tl_dg = ws + OFF_TL2;
        const int plane = tid >> 2;
        const int posq = (tid & 3) * 4;
        #pragma unroll
        for (int pass = 0; pass < 3; pass++){
            const int o = pass * 64 + plane;
            #pragma unroll
            for (int hf = 0; hf < 2; hf++){
                const int pq = hf * 16 + posq;
                float4 w0 = make_float4(g2[pq + 0][o], g2[pq + 0][192 + o],
                                        g2[pq + 1][o], g2[pq + 1][192 + o]);
                float4 w1 = make_float4(g2[pq + 2][o], g2[pq + 2][192 + o],
                                        g2[pq + 3][o], g2[pq + 3][192 + o]);
                float* base = &tl_dg[(size_t)(b * 192 + o) * 8192 + (size_t)(Q0 + pq) * 2];
                *(float4*)&base[0] = w0;
                *(float4*)&base[4] = w1;
            }
        }
        if (tid < 192){
            const int pl = tid >> 4;
            const int pos = tid & 15;
            float4 v0 = *(float4*)&g2[pos][384 + pl * 4];
            float4 v1 = *(float4*)&g2[16 + pos][384 + pl * 4];
            float4* dst = (float4*)(ws + OFF_BC4D) + (size_t)(b * 12 + pl) * 4096 + Q0 + pos;
            dst[0] = v0;
            dst[16] = v1;
        }
    }
}

// ---------------- diagonal wavefront scan (r14 structure, unchanged) ----------------
#define LOADSET(pfx, sv) do {                                                   \
    const int sc_ = (sv) < 126 ? (sv) : 126;                                    \
    const int jmin_ = (sc_ > 63) ? (sc_ - 63) : 0;                              \
    pfx##_q = diag_off(sc_) - jmin_ + j;                                        \
    pfx##_u = pu[pfx##_q];                                                      \
    pfx##_tv = ptl[pfx##_q];                                                    \
    pfx##_bt = pBT[pfx##_q]; pfx##_bl = pBL[pfx##_q]; pfx##_cc = pC[pfx##_q];   \
} while (0)

#define STEP(pfx, sv) do {                                                      \
    const float dT_ = pfx##_tv.x, dL_ = pfx##_tv.y, u_ = pfx##_u;               \
    const float bt_[4] = {pfx##_bt.x, pfx##_bt.y, pfx##_bt.z, pfx##_bt.w};      \
    const float bl_[4] = {pfx##_bl.x, pfx##_bl.y, pfx##_bl.z, pfx##_bl.w};      \
    const float cc_[4] = {pfx##_cc.x, pfx##_cc.y, pfx##_cc.z, pfx##_cc.w};      \
    const int q_ = pfx##_q;                                                     \
    LOADSET(pfx, (sv) + 4);                                                     \
    float da_[4], dl_[4];                                                       \
    if (sflag){                                                                 \
        const float E_ = __expf(-dT_), F_ = __expf(-dL_);                       \
        da_[0] = __expf(nA1 * dT_); dl_[0] = __expf(nA1 * dL_);                 \
        da_[1] = da_[0] * E_; da_[2] = da_[1] * E_; da_[3] = da_[2] * E_;       \
        dl_[1] = dl_[0] * F_; dl_[2] = dl_[1] * F_; dl_[3] = dl_[2] * F_;       \
    } else {                                                                    \
        da_[0] = __expf(dT_ * ATr[0]); da_[1] = __expf(dT_ * ATr[1]);           \
        da_[2] = __expf(dT_ * ATr[2]); da_[3] = __expf(dT_ * ATr[3]);           \
        dl_[0] = __expf(dL_ * ALr[0]); dl_[1] = __expf(dL_ * ALr[1]);           \
        dl_[2] = __expf(dL_ * ALr[2]); dl_[3] = __expf(dL_ * ALr[3]);           \
    }                                                                           \
    const int ic_ = (sv) - j;                                                   \
    const bool act_ = ((unsigned)ic_) < 64u;                                    \
    const float udT_ = u_ * dT_, udL_ = u_ * dL_;                               \
    float y_ = 0.f;                                                             \
    _Pragma("unroll")                                                           \
    for (int k = 0; k < 4; k++){                                                \
        float hl_ = __shfl_up(h[k], 1u, 64);                                    \
        hl_ = (j == 0) ? 0.f : hl_;                                             \
        float hn_ = fmaf(da_[k], h[k], fmaf(dl_[k], hl_, fmaf(udT_, bt_[k], udL_ * bl_[k]))); \
        h[k] = act_ ? hn_ : h[k];                                               \
        y_ = fmaf(hn_, cc_[k], y_);                                             \
    }                                                                           \
    if (act_) ylds[(wv << 12) + q_] = y_;                                       \
} while (0)

__global__ __launch_bounds__(256) void scan_k(const float* __restrict__ ATl,
                                              const float* __restrict__ ALl,
                                              const float* __restrict__ Dskp,
                                              float* __restrict__ ws){
    __shared__ float ylds[4 * 4096];            // 64 KB
    const int bd = blockIdx.x;
    const int b = bd / 192, d = bd - b * 192;
    const int tid = threadIdx.x;
    const int wv = tid >> 6, j = tid & 63;
    const int n0 = wv * 4;
    const int ng = wv;

    const float* __restrict__ pu = ws + OFF_DIAG + (size_t)bd * 4096;
    const float2* __restrict__ ptl = (const float2*)(ws + OFF_TL2 + (size_t)bd * 8192);
    const float4* __restrict__ bc4 = (const float4*)(ws + OFF_BC4D) + (size_t)(b * 12) * 4096;
    const float4* __restrict__ pBT = bc4 + (size_t)(0 + ng) * 4096;
    const float4* __restrict__ pBL = bc4 + (size_t)(4 + ng) * 4096;
    const float4* __restrict__ pC  = bc4 + (size_t)(8 + ng) * 4096;

    const bool sflag = (ws[OFF_FLAG] > 0.5f);
    const float nA1 = -(float)(n0 + 1);
    float ATr[4], ALr[4];
    if (!sflag){
        #pragma unroll
        for (int k = 0; k < 4; k++){
            ATr[k] = -expf(ATl[d * NS + n0 + k]);
            ALr[k] = -expf(ALl[d * NS + n0 + k]);
        }
    } else {
        #pragma unroll
        for (int k = 0; k < 4; k++){ ATr[k] = 0.f; ALr[k] = 0.f; }
    }
    float h[4] = {0.f, 0.f, 0.f, 0.f};

    int a_q, b_q, c_q, d_q;
    float a_u; float2 a_tv; float4 a_bt, a_bl, a_cc;
    float b_u; float2 b_tv; float4 b_bt, b_bl, b_cc;
    float c_u; float2 c_tv; float4 c_bt, c_bl, c_cc;
    float d_u; float2 d_tv; float4 d_bt, d_bl, d_cc;
    LOADSET(a, 0);
    LOADSET(b, 1);
    LOADSET(c, 2);
    LOADSET(d, 3);

    for (int s = 0; s < 128; s += 4){
        STEP(a, s);
        STEP(b, s + 1);
        STEP(c, s + 2);
        STEP(d, s + 3);
    }

    __syncthreads();
    const float Dsk = Dskp[d];
    for (int idx = tid; idx < 4096; idx += 256){
        const float v = ylds[idx] + ylds[4096 + idx] + ylds[8192 + idx] + ylds[12288 + idx]
                      + pu[idx] * Dsk;
        ylds[idx] = gelu_f(v);
    }
    __syncthreads();
    float* __restrict__ yg = ws + OFF_YG + (size_t)bd * 4096;
    for (int idx = tid; idx < 4096; idx += 256){
        const int i = idx >> 6, jj = idx & 63;
        const int s = i + jj;
        const int jmin = (s > 63) ? (s - 63) : 0;
        yg[idx] = ylds[diag_off(s) + jj - jmin];
    }
}

// ---------------- out projection via bf16x3 MFMA, 32 pos/block ----------------
__global__ __launch_bounds__(256, 1) void out_k(const float* __restrict__ Wob,
                                                float* __restrict__ ws,
                                                float* __restrict__ out){
    __shared__ float yg_t[32][196];             // 25 KB
    const unsigned short* __restrict__ wsu = (const unsigned short*)ws;
    const int P0 = blockIdx.x * 32;
    const int b = P0 >> 12;
    const int prel = P0 & 4095;
    const int tid = threadIdx.x;

    {
        const float* __restrict__ ygp = ws + OFF_YG;
        #pragma unroll
        for (int pass = 0; pass < 3; pass++){
            const int plane = pass * 64 + (tid >> 2);
            const int posq = (tid & 3) * 4;
            #pragma unroll
            for (int hf = 0; hf < 2; hf++){
                const int pq = hf * 16 + posq;
                float4 v = *(const float4*)&ygp[(size_t)(b * 192 + plane) * 4096 + prel + pq];
                yg_t[pq + 0][plane] = v.x;
                yg_t[pq + 1][plane] = v.y;
                yg_t[pq + 2][plane] = v.z;
                yg_t[pq + 3][plane] = v.w;
            }
        }
    }
    __syncthreads();

    const int wv = tid >> 6, lane = tid & 63;
    const int lr = lane & 15, lg = lane >> 4;

    short8v yh0[6], yl0[6], yh1[6], yl1[6];
    #pragma unroll
    for (int ks = 0; ks < 6; ks++){
        const float* yp0 = &yg_t[lr][ks * 32 + lg * 8];
        const float* yp1 = &yg_t[16 + lr][ks * 32 + lg * 8];
        split8(*(const float4*)yp0, *(const float4*)(yp0 + 4), yh0[ks], yl0[ks]);
        split8(*(const float4*)yp1, *(const float4*)(yp1 + 4), yh1[ks], yl1[ks]);
    }
    {
        floatx4 a00 = {0,0,0,0}, a01 = {0,0,0,0}, a02 = {0,0,0,0};
        floatx4 a10 = {0,0,0,0}, a11 = {0,0,0,0}, a12 = {0,0,0,0};
        const int n0 = wv * 48;
        #pragma unroll
        for (int ks = 0; ks < 6; ks++){
            const size_t rb = (size_t)(n0 + lr) * 192 + ks * 32 + lg * 8;
            const short8v bh0 = *(const short8v*)(wsu + SW_WOH + rb);
            const short8v bl0 = *(const short8v*)(wsu + SW_WOL + rb);
            const short8v bh1 = *(const short8v*)(wsu + SW_WOH + rb + 16*192);
            const short8v bl1 = *(const short8v*)(wsu + SW_WOL + rb + 16*192);
            const short8v bh2 = *(const short8v*)(wsu + SW_WOH + rb + 32*192);
            const short8v bl2 = *(const short8v*)(wsu + SW_WOL + rb + 32*192);
            a00 = __builtin_amdgcn_mfma_f32_16x16x32_bf16(yh0[ks], bh0, a00, 0, 0, 0);
            a10 = __builtin_amdgcn_mfma_f32_16x16x32_bf16(yh1[ks], bh0, a10, 0, 0, 0);
            a01 = __builtin_amdgcn_mfma_f32_16x16x32_bf16(yh0[ks], bh1, a01, 0, 0, 0);
            a11 = __builtin_amdgcn_mfma_f32_16x16x32_bf16(yh1[ks], bh1, a11, 0, 0, 0);
            a02 = __builtin_amdgcn_mfma_f32_16x16x32_bf16(yh0[ks], bh2, a02, 0, 0, 0);
            a12 = __builtin_amdgcn_mfma_f32_16x16x32_bf16(yh1[ks], bh2, a12, 0, 0, 0);
            a00 = __builtin_amdgcn_mfma_f32_16x16x32_bf16(yh0[ks], bl0, a00, 0, 0, 0);
            a10 = __builtin_amdgcn_mfma_f32_16x16x32_bf16(yh1[ks], bl0, a10, 0, 0, 0);
            a01 = __builtin_amdgcn_mfma_f32_16x16x32_bf16(yh0[ks], bl1, a01, 0, 0, 0);
            a11 = __builtin_amdgcn_mfma_f32_16x16x32_bf16(yh1[ks], bl1, a11, 0, 0, 0);
            a02 = __builtin_amdgcn_mfma_f32_16x16x32_bf16(yh0[ks], bl2, a02, 0, 0, 0);
            a12 = __builtin_amdgcn_mfma_f32_16x16x32_bf16(yh1[ks], bl2, a12, 0, 0, 0);
            a00 = __builtin_amdgcn_mfma_f32_16x16x32_bf16(yl0[ks], bh0, a00, 0, 0, 0);
            a10 = __builtin_amdgcn_mfma_f32_16x16x32_bf16(yl1[ks], bh0, a10, 0, 0, 0);
            a01 = __builtin_amdgcn_mfma_f32_16x16x32_bf16(yl0[ks], bh1, a01, 0, 0, 0);
            a11 = __builtin_amdgcn_mfma_f32_16x16x32_bf16(yl1[ks], bh1, a11, 0, 0, 0);
            a02 = __builtin_amdgcn_mfma_f32_16x16x32_bf16(yl0[ks], bh2, a02, 0, 0, 0);
            a12 = __builtin_amdgcn_mfma_f32_16x16x32_bf16(yl1[ks], bh2, a12, 0, 0, 0);
        }
        const float b0 = Wob[n0 + lr], b1 = Wob[n0 + 16 + lr], b2 = Wob[n0 + 32 + lr];
        #pragma unroll
        for (int r = 0; r < 4; r++){
            const int pos0 = P0 + lg * 4 + r;
            const int pos1 = pos0 + 16;
            out[(size_t)pos0 * 192 + n0 + lr]      = a00[r] + b0;
            out[(size_t)pos0 * 192 + n0 + 16 + lr] = a01[r] + b1;
            out[(size_t)pos0 * 192 + n0 + 32 + lr] = a02[r] + b2;
            out[(size_t)pos1 * 192 + n0 + lr]      = a10[r] + b0;
            out[(size_t)pos1 * 192 + n0 + 16 + lr] = a11[r] + b1;
            out[(size_t)pos1 * 192 + n0 + 32 + lr] = a12[r] + b2;
        }
    }
}

extern "C" void kernel_launch(void* const* d_in, const int* in_sizes, int n_in,
                              void* d_out, int out_size, void* d_ws, size_t ws_size,
                              hipStream_t stream) {
    const float* x    = (const float*)d_in[0];
    const float* Win  = (const float*)d_in[1];
    const float* Winb = (const float*)d_in[2];
    const float* xpw  = (const float*)d_in[3];
    const float* dtTw = (const float*)d_in[4];
    const float* dtTb = (const float*)d_in[5];
    const float* dtLw = (const float*)d_in[6];
    const float* dtLb = (const float*)d_in[7];
    const float* ATl  = (const float*)d_in[8];
    const float* ALl  = (const float*)d_in[9];
    const float* Dsk  = (const float*)d_in[10];
    const float* Wo   = (const float*)d_in[11];
    const float* Wob  = (const float*)d_in[12];
    float* out = (float*)d_out;
    float* ws  = (float*)d_ws;

    hipLaunchKernelGGL(xsplit_k, dim3(1536), dim3(256), 0, stream, x, ws);
    hipLaunchKernelGGL(prep_k,   dim3(613),  dim3(256), 0, stream, Win, xpw, dtTw, dtLw, Wo, ATl, ALl, ws);
    hipLaunchKernelGGL(proj_k,   dim3(256),  dim3(256), 0, stream, Winb, dtTb, dtLb, ws);
    hipLaunchKernelGGL(scan_k,   dim3(384),  dim3(256), 0, stream, ATl, ALl, Dsk, ws);
    hipLaunchKernelGGL(out_k,    dim3(256),  dim3(256), 0, stream, Wob, ws, out);
}

// Round 19
// 112.196 us; speedup vs baseline: 1.0539x; 1.0539x over previous
//
#include <hip/hip_runtime.h>
#include <math.h>

#define DM 192
#define RNK 12
#define NS 16
#define NO2 432

// workspace float offsets (41.5 MB footprint)
#define OFF_FLAG   156672u
#define OFF_YG     3302416u           // scan output (fused ysum), row-major planes [bd][4096] f32
#define OFF_DIAG   5268496u           // 384 u diag planes [bd][4096] f32 (proj writes directly)
#define OFF_TL2    6841360u           // 384 (dT,dL) float2 diag planes [bd][8192] f32
#define OFF_BC4D   9987088u           // 24 f32 float4-cell diag planes [b*12+grp][4096][4]

typedef __attribute__((ext_vector_type(8))) short short8v;
typedef __attribute__((ext_vector_type(4))) float floatx4;

__device__ __forceinline__ float gelu_f(float x){
    return 0.5f * x * (1.0f + erff(x * 0.70710678118654752f));
}
__device__ __forceinline__ float softplus_f(float x){
    return fmaxf(x, 0.0f) + log1pf(__expf(-fabsf(x)));
}
__device__ __forceinline__ int diag_off(int s){
    return (s <= 64) ? ((s * (s + 1)) >> 1) : (2080 + (((s - 64) * (191 - s)) >> 1));
}
// inverse map: packed index q -> (i,j)
__device__ __forceinline__ void inv_diag(int q, int& i_out, int& j_out){
    int s;
    if (q < 2080){
        s = (int)((sqrtf(8.0f * (float)q + 1.0f) - 1.0f) * 0.5f);
        while (((s + 1) * (s + 2)) / 2 <= q) s++;
        while ((s * (s + 1)) / 2 > q) s--;
    } else {
        const int q2 = 4095 - q;
        int t = (int)((sqrtf(8.0f * (float)q2 + 1.0f) - 1.0f) * 0.5f);
        while (((t + 1) * (t + 2)) / 2 <= q2) t++;
        while ((t * (t + 1)) / 2 > q2) t--;
        s = 126 - t;
    }
    const int jmin = (s > 63) ? (s - 63) : 0;
    const int j = jmin + (q - diag_off(s));
    j_out = j;
    i_out = s - j;
}
__device__ __forceinline__ unsigned short bf16_rte(float f){
    unsigned u = __float_as_uint(f);
    unsigned r = (u + 0x7fffu + ((u >> 16) & 1u)) >> 16;
    return (unsigned short)r;
}
__device__ __forceinline__ float bf16_f(unsigned short h){
    return __uint_as_float(((unsigned)h) << 16);
}
__device__ __forceinline__ void split8(float4 v0, float4 v1, short8v& hi, short8v& lo){
    float f[8] = {v0.x, v0.y, v0.z, v0.w, v1.x, v1.y, v1.z, v1.w};
    #pragma unroll
    for (int e = 0; e < 8; e++){
        unsigned short h = bf16_rte(f[e]);
        hi[e] = (short)h;
        lo[e] = (short)bf16_rte(f[e] - bf16_f(h));
    }
}

// ---------------- prep: bf16 hi/lo weight splits + A-structure flag ----------------
#define SW_WINH 0u
#define SW_WINL 36864u
#define SW_WCH  73728u
#define SW_WCL  156672u
#define SW_WOH  239616u
#define SW_WOL  276480u

__global__ __launch_bounds__(256) void prep_k(const float* __restrict__ Win,
                                              const float* __restrict__ xpw,
                                              const float* __restrict__ dtwT,
                                              const float* __restrict__ dtwL,
                                              const float* __restrict__ Wout,
                                              const float* __restrict__ ATl,
                                              const float* __restrict__ ALl,
                                              float* __restrict__ ws){
    unsigned short* __restrict__ wsu = (unsigned short*)ws;
    if (blockIdx.x == 612){
        __shared__ int okf;
        if (threadIdx.x == 0) okf = 1;
        __syncthreads();
        bool ok = true;
        for (int t = threadIdx.x; t < 6144; t += 256){
            const float* arr = (t < 3072) ? ATl : ALl;
            int e = (t < 3072) ? t : t - 3072;
            int n = e & 15;
            ok = ok && (fabsf(arr[e] - logf((float)(n + 1))) < 1e-5f);
        }
        if (!ok) atomicAnd(&okf, 0);
        __syncthreads();
        if (threadIdx.x == 0) ws[OFF_FLAG] = okf ? 1.0f : 0.0f;
        return;
    }
    int idx = blockIdx.x * 256 + threadIdx.x;
    float w;
    unsigned hioff, looff, rel;
    if (idx < 36864){
        w = Win[idx]; hioff = SW_WINH; looff = SW_WINL; rel = idx;
    } else if (idx < 119808){
        int t = idx - 36864;
        int o = t / DM, c = t - o * DM;
        float acc = 0.f;
        if (o < 192){
            #pragma unroll
            for (int r = 0; r < RNK; r++) acc += dtwT[o * RNK + r] * xpw[r * DM + c];
        } else if (o < 384){
            int d2 = o - 192;
            #pragma unroll
            for (int r = 0; r < RNK; r++) acc += dtwL[d2 * RNK + r] * xpw[(RNK + r) * DM + c];
        } else {
            acc = xpw[(2 * RNK + (o - 384)) * DM + c];
        }
        w = acc; hioff = SW_WCH; looff = SW_WCL; rel = t;
    } else if (idx < 156672){
        int t = idx - 119808;
        w = Wout[t]; hioff = SW_WOH; looff = SW_WOL; rel = t;
    } else return;
    unsigned short h = bf16_rte(w);
    wsu[hioff + rel] = h;
    wsu[looff + rel] = bf16_rte(w - bf16_f(h));
}

// ---------------- fused projections via bf16x3 MFMA, 32 pos/block, DIAG-DIRECT stores ----
__global__ __launch_bounds__(256, 1) void proj_k(const float* __restrict__ x,
                                                 const float* __restrict__ inb,
                                                 const float* __restrict__ dtTb,
                                                 const float* __restrict__ dtLb,
                                                 float* __restrict__ ws){
    __shared__ float u_t[32][196];              // 25 KB
    __shared__ float g2[32][436];               // 56 KB
    const unsigned short* __restrict__ wsu = (const unsigned short*)ws;
    const int bx = blockIdx.x;
    const int b = bx >> 7;
    const int Q0 = (bx & 127) * 32;
    const int tid = threadIdx.x;
    const int wv = tid >> 6, lane = tid & 63;
    const int lr = lane & 15, lg = lane >> 4;

    int ic0, jc0, ic1, jc1;
    inv_diag(Q0 + lr, ic0, jc0);
    inv_diag(Q0 + 16 + lr, ic1, jc1);
    const size_t xrow0 = ((size_t)(b << 12) + (size_t)(ic0 * 64 + jc0)) * 192;
    const size_t xrow1 = ((size_t)(b << 12) + (size_t)(ic1 * 64 + jc1)) * 192;

    // ---- G1: u = gelu(x @ Win^T + b), two pos-groups ----
    short8v xh0[6], xl0[6], xh1[6], xl1[6];
    #pragma unroll
    for (int ks = 0; ks < 6; ks++){
        const float* xp0 = x + xrow0 + ks * 32 + lg * 8;
        const float* xp1 = x + xrow1 + ks * 32 + lg * 8;
        split8(*(const float4*)xp0, *(const float4*)(xp0 + 4), xh0[ks], xl0[ks]);
        split8(*(const float4*)xp1, *(const float4*)(xp1 + 4), xh1[ks], xl1[ks]);
    }
    {
        floatx4 a00 = {0,0,0,0}, a01 = {0,0,0,0}, a02 = {0,0,0,0};
        floatx4 a10 = {0,0,0,0}, a11 = {0,0,0,0}, a12 = {0,0,0,0};
        const int n0 = wv * 48;
        #pragma unroll
        for (int ks = 0; ks < 6; ks++){
            const size_t rb = (size_t)(n0 + lr) * 192 + ks * 32 + lg * 8;
            const short8v bh0 = *(const short8v*)(wsu + SW_WINH + rb);
            const short8v bl0 = *(const short8v*)(wsu + SW_WINL + rb);
            const short8v bh1 = *(const short8v*)(wsu + SW_WINH + rb + 16*192);
            const short8v bl1 = *(const short8v*)(wsu + SW_WINL + rb + 16*192);
            const short8v bh2 = *(const short8v*)(wsu + SW_WINH + rb + 32*192);
            const short8v bl2 = *(const short8v*)(wsu + SW_WINL + rb + 32*192);
            a00 = __builtin_amdgcn_mfma_f32_16x16x32_bf16(xh0[ks], bh0, a00, 0, 0, 0);
            a10 = __builtin_amdgcn_mfma_f32_16x16x32_bf16(xh1[ks], bh0, a10, 0, 0, 0);
            a01 = __builtin_amdgcn_mfma_f32_16x16x32_bf16(xh0[ks], bh1, a01, 0, 0, 0);
            a11 = __builtin_amdgcn_mfma_f32_16x16x32_bf16(xh1[ks], bh1, a11, 0, 0, 0);
            a02 = __builtin_amdgcn_mfma_f32_16x16x32_bf16(xh0[ks], bh2, a02, 0, 0, 0);
            a12 = __builtin_amdgcn_mfma_f32_16x16x32_bf16(xh1[ks], bh2, a12, 0, 0, 0);
            a00 = __builtin_amdgcn_mfma_f32_16x16x32_bf16(xh0[ks], bl0, a00, 0, 0, 0);
            a10 = __builtin_amdgcn_mfma_f32_16x16x32_bf16(xh1[ks], bl0, a10, 0, 0, 0);
            a01 = __builtin_amdgcn_mfma_f32_16x16x32_bf16(xh0[ks], bl1, a01, 0, 0, 0);
            a11 = __builtin_amdgcn_mfma_f32_16x16x32_bf16(xh1[ks], bl1, a11, 0, 0, 0);
            a02 = __builtin_amdgcn_mfma_f32_16x16x32_bf16(xh0[ks], bl2, a02, 0, 0, 0);
            a12 = __builtin_amdgcn_mfma_f32_16x16x32_bf16(xh1[ks], bl2, a12, 0, 0, 0);
            a00 = __builtin_amdgcn_mfma_f32_16x16x32_bf16(xl0[ks], bh0, a00, 0, 0, 0);
            a10 = __builtin_amdgcn_mfma_f32_16x16x32_bf16(xl1[ks], bh0, a10, 0, 0, 0);
            a01 = __builtin_amdgcn_mfma_f32_16x16x32_bf16(xl0[ks], bh1, a01, 0, 0, 0);
            a11 = __builtin_amdgcn_mfma_f32_16x16x32_bf16(xl1[ks], bh1, a11, 0, 0, 0);
            a02 = __builtin_amdgcn_mfma_f32_16x16x32_bf16(xl0[ks], bh2, a02, 0, 0, 0);
            a12 = __builtin_amdgcn_mfma_f32_16x16x32_bf16(xl1[ks], bh2, a12, 0, 0, 0);
        }
        const float b0 = inb[n0 + lr], b1 = inb[n0 + 16 + lr], b2 = inb[n0 + 32 + lr];
        #pragma unroll
        for (int r = 0; r < 4; r++){
            const int pl = lg * 4 + r;
            u_t[pl][n0 + lr]           = gelu_f(a00[r] + b0);
            u_t[pl][n0 + 16 + lr]      = gelu_f(a01[r] + b1);
            u_t[pl][n0 + 32 + lr]      = gelu_f(a02[r] + b2);
            u_t[16 + pl][n0 + lr]      = gelu_f(a10[r] + b0);
            u_t[16 + pl][n0 + 16 + lr] = gelu_f(a11[r] + b1);
            u_t[16 + pl][n0 + 32 + lr] = gelu_f(a12[r] + b2);
        }
    }
    __syncthreads();

    // coalesced u diag-plane stores (f32): 3 plane passes x 2 pos halves
    {
        float* __restrict__ u_dg = ws + OFF_DIAG;
        #pragma unroll
        for (int pass = 0; pass < 3; pass++){
            const int plane = pass * 64 + (tid >> 2);
            const int posq = (tid & 3) * 4;
            #pragma unroll
            for (int hf = 0; hf < 2; hf++){
                const int pq = hf * 16 + posq;
                float4 v = make_float4(u_t[pq + 0][plane], u_t[pq + 1][plane],
                                       u_t[pq + 2][plane], u_t[pq + 3][plane]);
                *(float4*)&u_dg[(size_t)(b * 192 + plane) * 4096 + Q0 + pq] = v;
            }
        }
    }

    // ---- G2: [dT | dL | BC] = u @ Wcomb^T, two pos-groups ----
    short8v uh0[6], ul0[6], uh1[6], ul1[6];
    #pragma unroll
    for (int ks = 0; ks < 6; ks++){
        const float* up0 = &u_t[lr][ks * 32 + lg * 8];
        const float* up1 = &u_t[16 + lr][ks * 32 + lg * 8];
        split8(*(const float4*)up0, *(const float4*)(up0 + 4), uh0[ks], ul0[ks]);
        split8(*(const float4*)up1, *(const float4*)(up1 + 4), uh1[ks], ul1[ks]);
    }
    const int t0 = wv * 7;
    const int cnt = (wv == 3) ? 6 : 7;
    for (int tp = 0; tp < cnt; tp++){
        const int n0a = (t0 + tp) * 16;
        floatx4 g0 = {0,0,0,0}, g1 = {0,0,0,0};
        #pragma unroll
        for (int ks = 0; ks < 6; ks++){
            const size_t ra = (size_t)(n0a + lr) * 192 + ks * 32 + lg * 8;
            const short8v bhA = *(const short8v*)(wsu + SW_WCH + ra);
            const short8v blA = *(const short8v*)(wsu + SW_WCL + ra);
            g0 = __builtin_amdgcn_mfma_f32_16x16x32_bf16(uh0[ks], bhA, g0, 0, 0, 0);
            g1 = __builtin_amdgcn_mfma_f32_16x16x32_bf16(uh1[ks], bhA, g1, 0, 0, 0);
            g0 = __builtin_amdgcn_mfma_f32_16x16x32_bf16(uh0[ks], blA, g0, 0, 0, 0);
            g1 = __builtin_amdgcn_mfma_f32_16x16x32_bf16(uh1[ks], blA, g1, 0, 0, 0);
            g0 = __builtin_amdgcn_mfma_f32_16x16x32_bf16(ul0[ks], bhA, g0, 0, 0, 0);
            g1 = __builtin_amdgcn_mfma_f32_16x16x32_bf16(ul1[ks], bhA, g1, 0, 0, 0);
        }
        const int o = n0a + lr;
        float bb = 0.f; int mode = 2;
        if (o < 192){ bb = dtTb[o]; mode = 0; }
        else if (o < 384){ bb = dtLb[o - 192]; mode = 1; }
        #pragma unroll
        for (int r = 0; r < 4; r++){
            float v0 = g0[r], v1 = g1[r];
            if (mode < 2){ v0 = softplus_f(v0 + bb); v1 = softplus_f(v1 + bb); }
            g2[lg * 4 + r][o] = v0;
            g2[16 + lg * 4 + r][o] = v1;
        }
    }
    __syncthreads();

    // coalesced interleaved (dT,dL) diag stores + BC diag stores
    {
        float* __restrict__ tl_dg = ws + OFF_TL2;
        const int plane = tid >> 2;
        const int posq = (tid & 3) * 4;
        #pragma unroll
        for (int pass = 0; pass < 3; pass++){
            const int o = pass * 64 + plane;
            #pragma unroll
            for (int hf = 0; hf < 2; hf++){
                const int pq = hf * 16 + posq;
                float4 w0 = make_float4(g2[pq + 0][o], g2[pq + 0][192 + o],
                                        g2[pq + 1][o], g2[pq + 1][192 + o]);
                float4 w1 = make_float4(g2[pq + 2][o], g2[pq + 2][192 + o],
                                        g2[pq + 3][o], g2[pq + 3][192 + o]);
                float* base = &tl_dg[(size_t)(b * 192 + o) * 8192 + (size_t)(Q0 + pq) * 2];
                *(float4*)&base[0] = w0;
                *(float4*)&base[4] = w1;
            }
        }
        if (tid < 192){
            const int pl = tid >> 4;
            const int pos = tid & 15;
            float4 v0 = *(float4*)&g2[pos][384 + pl * 4];
            float4 v1 = *(float4*)&g2[16 + pos][384 + pl * 4];
            float4* dst = (float4*)(ws + OFF_BC4D) + (size_t)(b * 12 + pl) * 4096 + Q0 + pos;
            dst[0] = v0;
            dst[16] = v1;
        }
    }
}

// ---------------- diagonal wavefront scan (r14 structure, unchanged) ----------------
#define LOADSET(pfx, sv) do {                                                   \
    const int sc_ = (sv) < 126 ? (sv) : 126;                                    \
    const int jmin_ = (sc_ > 63) ? (sc_ - 63) : 0;                              \
    pfx##_q = diag_off(sc_) - jmin_ + j;                                        \
    pfx##_u = pu[pfx##_q];                                                      \
    pfx##_tv = ptl[pfx##_q];                                                    \
    pfx##_bt = pBT[pfx##_q]; pfx##_bl = pBL[pfx##_q]; pfx##_cc = pC[pfx##_q];   \
} while (0)

#define STEP(pfx, sv) do {                                                      \
    const float dT_ = pfx##_tv.x, dL_ = pfx##_tv.y, u_ = pfx##_u;               \
    const float bt_[4] = {pfx##_bt.x, pfx##_bt.y, pfx##_bt.z, pfx##_bt.w};      \
    const float bl_[4] = {pfx##_bl.x, pfx##_bl.y, pfx##_bl.z, pfx##_bl.w};      \
    const float cc_[4] = {pfx##_cc.x, pfx##_cc.y, pfx##_cc.z, pfx##_cc.w};      \
    const int q_ = pfx##_q;                                                     \
    LOADSET(pfx, (sv) + 4);                                                     \
    float da_[4], dl_[4];                                                       \
    if (sflag){                                                                 \
        const float E_ = __expf(-dT_), F_ = __expf(-dL_);                       \
        da_[0] = __expf(nA1 * dT_); dl_[0] = __expf(nA1 * dL_);                 \
        da_[1] = da_[0] * E_; da_[2] = da_[1] * E_; da_[3] = da_[2] * E_;       \
        dl_[1] = dl_[0] * F_; dl_[2] = dl_[1] * F_; dl_[3] = dl_[2] * F_;       \
    } else {                                                                    \
        da_[0] = __expf(dT_ * ATr[0]); da_[1] = __expf(dT_ * ATr[1]);           \
        da_[2] = __expf(dT_ * ATr[2]); da_[3] = __expf(dT_ * ATr[3]);           \
        dl_[0] = __expf(dL_ * ALr[0]); dl_[1] = __expf(dL_ * ALr[1]);           \
        dl_[2] = __expf(dL_ * ALr[2]); dl_[3] = __expf(dL_ * ALr[3]);           \
    }                                                                           \
    const int ic_ = (sv) - j;                                                   \
    const bool act_ = ((unsigned)ic_) < 64u;                                    \
    const float udT_ = u_ * dT_, udL_ = u_ * dL_;                               \
    float y_ = 0.f;                                                             \
    _Pragma("unroll")                                                           \
    for (int k = 0; k < 4; k++){                                                \
        float hl_ = __shfl_up(h[k], 1u, 64);                                    \
        hl_ = (j == 0) ? 0.f : hl_;                                             \
        float hn_ = fmaf(da_[k], h[k], fmaf(dl_[k], hl_, fmaf(udT_, bt_[k], udL_ * bl_[k]))); \
        h[k] = act_ ? hn_ : h[k];                                               \
        y_ = fmaf(hn_, cc_[k], y_);                                             \
    }                                                                           \
    if (act_) ylds[(wv << 12) + q_] = y_;                                       \
} while (0)

__global__ __launch_bounds__(256) void scan_k(const float* __restrict__ ATl,
                                              const float* __restrict__ ALl,
                                              const float* __restrict__ Dskp,
                                              float* __restrict__ ws){
    __shared__ float ylds[4 * 4096];            // 64 KB
    const int bd = blockIdx.x;
    const int b = bd / 192, d = bd - b * 192;
    const int tid = threadIdx.x;
    const int wv = tid >> 6, j = tid & 63;
    const int n0 = wv * 4;
    const int ng = wv;

    const float* __restrict__ pu = ws + OFF_DIAG + (size_t)bd * 4096;
    const float2* __restrict__ ptl = (const float2*)(ws + OFF_TL2 + (size_t)bd * 8192);
    const float4* __restrict__ bc4 = (const float4*)(ws + OFF_BC4D) + (size_t)(b * 12) * 4096;
    const float4* __restrict__ pBT = bc4 + (size_t)(0 + ng) * 4096;
    const float4* __restrict__ pBL = bc4 + (size_t)(4 + ng) * 4096;
    const float4* __restrict__ pC  = bc4 + (size_t)(8 + ng) * 4096;

    const bool sflag = (ws[OFF_FLAG] > 0.5f);
    const float nA1 = -(float)(n0 + 1);
    float ATr[4], ALr[4];
    if (!sflag){
        #pragma unroll
        for (int k = 0; k < 4; k++){
            ATr[k] = -expf(ATl[d * NS + n0 + k]);
            ALr[k] = -expf(ALl[d * NS + n0 + k]);
        }
    } else {
        #pragma unroll
        for (int k = 0; k < 4; k++){ ATr[k] = 0.f; ALr[k] = 0.f; }
    }
    float h[4] = {0.f, 0.f, 0.f, 0.f};

    int a_q, b_q, c_q, d_q;
    float a_u; float2 a_tv; float4 a_bt, a_bl, a_cc;
    float b_u; float2 b_tv; float4 b_bt, b_bl, b_cc;
    float c_u; float2 c_tv; float4 c_bt, c_bl, c_cc;
    float d_u; float2 d_tv; float4 d_bt, d_bl, d_cc;
    LOADSET(a, 0);
    LOADSET(b, 1);
    LOADSET(c, 2);
    LOADSET(d, 3);

    for (int s = 0; s < 128; s += 4){
        STEP(a, s);
        STEP(b, s + 1);
        STEP(c, s + 2);
        STEP(d, s + 3);
    }

    __syncthreads();
    const float Dsk = Dskp[d];
    for (int idx = tid; idx < 4096; idx += 256){
        const float v = ylds[idx] + ylds[4096 + idx] + ylds[8192 + idx] + ylds[12288 + idx]
                      + pu[idx] * Dsk;
        ylds[idx] = gelu_f(v);
    }
    __syncthreads();
    float* __restrict__ yg = ws + OFF_YG + (size_t)bd * 4096;
    for (int idx = tid; idx < 4096; idx += 256){
        const int i = idx >> 6, jj = idx & 63;
        const int s = i + jj;
        const int jmin = (s > 63) ? (s - 63) : 0;
        yg[idx] = ylds[diag_off(s) + jj - jmin];
    }
}

// ---------------- out projection via bf16x3 MFMA, 32 pos/block ----------------
__global__ __launch_bounds__(256, 1) void out_k(const float* __restrict__ Wob,
                                                float* __restrict__ ws,
                                                float* __restrict__ out){
    __shared__ float yg_t[32][196];             // 25 KB
    const unsigned short* __restrict__ wsu = (const unsigned short*)ws;
    const int P0 = blockIdx.x * 32;
    const int b = P0 >> 12;
    const int prel = P0 & 4095;
    const int tid = threadIdx.x;

    {
        const float* __restrict__ ygp = ws + OFF_YG;
        #pragma unroll
        for (int pass = 0; pass < 3; pass++){
            const int plane = pass * 64 + (tid >> 2);
            const int posq = (tid & 3) * 4;
            #pragma unroll
            for (int hf = 0; hf < 2; hf++){
                const int pq = hf * 16 + posq;
                float4 v = *(const float4*)&ygp[(size_t)(b * 192 + plane) * 4096 + prel + pq];
                yg_t[pq + 0][plane] = v.x;
                yg_t[pq + 1][plane] = v.y;
                yg_t[pq + 2][plane] = v.z;
                yg_t[pq + 3][plane] = v.w;
            }
        }
    }
    __syncthreads();

    const int wv = tid >> 6, lane = tid & 63;
    const int lr = lane & 15, lg = lane >> 4;

    short8v yh0[6], yl0[6], yh1[6], yl1[6];
    #pragma unroll
    for (int ks = 0; ks < 6; ks++){
        const float* yp0 = &yg_t[lr][ks * 32 + lg * 8];
        const float* yp1 = &yg_t[16 + lr][ks * 32 + lg * 8];
        split8(*(const float4*)yp0, *(const float4*)(yp0 + 4), yh0[ks], yl0[ks]);
        split8(*(const float4*)yp1, *(const float4*)(yp1 + 4), yh1[ks], yl1[ks]);
    }
    {
        floatx4 a00 = {0,0,0,0}, a01 = {0,0,0,0}, a02 = {0,0,0,0};
        floatx4 a10 = {0,0,0,0}, a11 = {0,0,0,0}, a12 = {0,0,0,0};
        const int n0 = wv * 48;
        #pragma unroll
        for (int ks = 0; ks < 6; ks++){
            const size_t rb = (size_t)(n0 + lr) * 192 + ks * 32 + lg * 8;
            const short8v bh0 = *(const short8v*)(wsu + SW_WOH + rb);
            const short8v bl0 = *(const short8v*)(wsu + SW_WOL + rb);
            const short8v bh1 = *(const short8v*)(wsu + SW_WOH + rb + 16*192);
            const short8v bl1 = *(const short8v*)(wsu + SW_WOL + rb + 16*192);
            const short8v bh2 = *(const short8v*)(wsu + SW_WOH + rb + 32*192);
            const short8v bl2 = *(const short8v*)(wsu + SW_WOL + rb + 32*192);
            a00 = __builtin_amdgcn_mfma_f32_16x16x32_bf16(yh0[ks], bh0, a00, 0, 0, 0);
            a10 = __builtin_amdgcn_mfma_f32_16x16x32_bf16(yh1[ks], bh0, a10, 0, 0, 0);
            a01 = __builtin_amdgcn_mfma_f32_16x16x32_bf16(yh0[ks], bh1, a01, 0, 0, 0);
            a11 = __builtin_amdgcn_mfma_f32_16x16x32_bf16(yh1[ks], bh1, a11, 0, 0, 0);
            a02 = __builtin_amdgcn_mfma_f32_16x16x32_bf16(yh0[ks], bh2, a02, 0, 0, 0);
            a12 = __builtin_amdgcn_mfma_f32_16x16x32_bf16(yh1[ks], bh2, a12, 0, 0, 0);
            a00 = __builtin_amdgcn_mfma_f32_16x16x32_bf16(yh0[ks], bl0, a00, 0, 0, 0);
            a10 = __builtin_amdgcn_mfma_f32_16x16x32_bf16(yh1[ks], bl0, a10, 0, 0, 0);
            a01 = __builtin_amdgcn_mfma_f32_16x16x32_bf16(yh0[ks], bl1, a01, 0, 0, 0);
            a11 = __builtin_amdgcn_mfma_f32_16x16x32_bf16(yh1[ks], bl1, a11, 0, 0, 0);
            a02 = __builtin_amdgcn_mfma_f32_16x16x32_bf16(yh0[ks], bl2, a02, 0, 0, 0);
            a12 = __builtin_amdgcn_mfma_f32_16x16x32_bf16(yh1[ks], bl2, a12, 0, 0, 0);
            a00 = __builtin_amdgcn_mfma_f32_16x16x32_bf16(yl0[ks], bh0, a00, 0, 0, 0);
            a10 = __builtin_amdgcn_mfma_f32_16x16x32_bf16(yl1[ks], bh0, a10, 0, 0, 0);
            a01 = __builtin_amdgcn_mfma_f32_16x16x32_bf16(yl0[ks], bh1, a01, 0, 0, 0);
            a11 = __builtin_amdgcn_mfma_f32_16x16x32_bf16(yl1[ks], bh1, a11, 0, 0, 0);
            a02 = __builtin_amdgcn_mfma_f32_16x16x32_bf16(yl0[ks], bh2, a02, 0, 0, 0);
            a12 = __builtin_amdgcn_mfma_f32_16x16x32_bf16(yl1[ks], bh2, a12, 0, 0, 0);
        }
        const float b0 = Wob[n0 + lr], b1 = Wob[n0 + 16 + lr], b2 = Wob[n0 + 32 + lr];
        #pragma unroll
        for (int r = 0; r < 4; r++){
            const int pos0 = P0 + lg * 4 + r;
            const int pos1 = pos0 + 16;
            out[(size_t)pos0 * 192 + n0 + lr]      = a00[r] + b0;
            out[(size_t)pos0 * 192 + n0 + 16 + lr] = a01[r] + b1;
            out[(size_t)pos0 * 192 + n0 + 32 + lr] = a02[r] + b2;
            out[(size_t)pos1 * 192 + n0 + lr]      = a10[r] + b0;
            out[(size_t)pos1 * 192 + n0 + 16 + lr] = a11[r] + b1;
            out[(size_t)pos1 * 192 + n0 + 32 + lr] = a12[r] + b2;
        }
    }
}

extern "C" void kernel_launch(void* const* d_in, const int* in_sizes, int n_in,
                              void* d_out, int out_size, void* d_ws, size_t ws_size,
                              hipStream_t stream) {
    const float* x    = (const float*)d_in[0];
    const float* Win  = (const float*)d_in[1];
    const float* Winb = (const float*)d_in[2];
    const float* xpw  = (const float*)d_in[3];
    const float* dtTw = (const float*)d_in[4];
    const float* dtTb = (const float*)d_in[5];
    const float* dtLw = (const float*)d_in[6];
    const float* dtLb = (const float*)d_in[7];
    const float* ATl  = (const float*)d_in[8];
    const float* ALl  = (const float*)d_in[9];
    const float* Dsk  = (const float*)d_in[10];
    const float* Wo   = (const float*)d_in[11];
    const float* Wob  = (const float*)d_in[12];
    float* out = (float*)d_out;
    float* ws  = (float*)d_ws;

    hipLaunchKernelGGL(prep_k,   dim3(613), dim3(256), 0, stream, Win, xpw, dtTw, dtLw, Wo, ATl, ALl, ws);
    hipLaunchKernelGGL(proj_k,   dim3(256), dim3(256), 0, stream, x, Winb, dtTb, dtLb, ws);
    hipLaunchKernelGGL(scan_k,   dim3(384), dim3(256), 0, stream, ATl, ALl, Dsk, ws);
    hipLaunchKernelGGL(out_k,    dim3(256), dim3(256), 0, stream, Wob, ws, out);
}